// Round 2
// baseline (3417.365 us; speedup 1.0000x reference)
//
#include <hip/hip_runtime.h>
#include <stdint.h>

// Problem constants (fixed by the reference)
#define NROUTE 2
#define NB 4
#define NT 2048
#define ND 1024
#define NKQK 512
#define NVV 8192
#define NTOPK 8
#define NBT (NB*NT)   // 8192 tokens

// Persistent device scratch (module-scope; fully rewritten every call).
__device__ unsigned long long g_enc_q[NROUTE*NBT];
__device__ unsigned long long g_enc_k[NROUTE*NBT];
__device__ unsigned long long g_enc_v[NROUTE*NBT];
__device__ int g_tab_idx[NROUTE*NB*NKQK*NTOPK];
__device__ int g_tab_val[NROUTE*NB*NKQK*NTOPK];

__global__ __launch_bounds__(256) void zero_enc_kernel() {
  int i = blockIdx.x * 256 + threadIdx.x;
  if (i < NROUTE*NBT) { g_enc_q[i] = 0ull; g_enc_k[i] = 0ull; g_enc_v[i] = 0ull; }
}

// Fused GEMM + running argmax.  score[token, v] = sum_d x[token,d] * W[v,d].
// 128x128 tile per block (256 threads, 8x8 per thread, K-step 32).
// Thread (cx,cy) owns tokens {cy*4+i, 64+cy*4+i} x vocab {cx*4+j, 64+cx*4+j}
// (split float4 groups -> 2-way LDS bank aliasing = free).
// Per-token best merged across blocks via 64-bit atomicMax of
// (monotone_score_bits << 32) | ~idx  -> max score, then SMALLEST index on
// ties (matches jnp.argmax first-occurrence semantics).
__global__ __launch_bounds__(256) void proj_argmax_kernel(
    const float* __restrict__ x, const float* __restrict__ W, int V, int sel)
{
  __shared__ float Xs[32][128];   // [k][token]
  __shared__ float Ws[32][128];   // [k][vocab]
  unsigned long long* enc = (sel == 0) ? g_enc_q : (sel == 1) ? g_enc_k : g_enc_v;

  const int m     = blockIdx.z;
  const int tbase = blockIdx.x * 128;
  const int vbase = blockIdx.y * 128;

  const int tid  = threadIdx.x;
  const int cx   = tid & 15;
  const int cy   = tid >> 4;
  const int srow = tid >> 1;           // staging row 0..127
  const int skof = (tid & 1) << 4;     // staging k offset (16 floats)

  const float* xp = x + (size_t)(tbase + srow) * ND + skof;
  const float* wp = W + (size_t)m * V * ND + (size_t)(vbase + srow) * ND + skof;

  float acc[8][8];
  #pragma unroll
  for (int i = 0; i < 8; i++)
    #pragma unroll
    for (int j = 0; j < 8; j++) acc[i][j] = 0.0f;

  for (int kd = 0; kd < ND; kd += 32) {
    const float4* xv = (const float4*)(xp + kd);
    const float4* wv = (const float4*)(wp + kd);
    float4 xr[4], wr[4];
    #pragma unroll
    for (int q = 0; q < 4; q++) { xr[q] = xv[q]; wr[q] = wv[q]; }

    __syncthreads();   // previous tile fully consumed
    #pragma unroll
    for (int q = 0; q < 4; q++) {
      int k0 = skof + q * 4;
      Xs[k0+0][srow] = xr[q].x; Xs[k0+1][srow] = xr[q].y;
      Xs[k0+2][srow] = xr[q].z; Xs[k0+3][srow] = xr[q].w;
      Ws[k0+0][srow] = wr[q].x; Ws[k0+1][srow] = wr[q].y;
      Ws[k0+2][srow] = wr[q].z; Ws[k0+3][srow] = wr[q].w;
    }
    __syncthreads();

    #pragma unroll 8
    for (int kk = 0; kk < 32; kk++) {
      float4 a0 = *(const float4*)&Xs[kk][cy << 2];
      float4 a1 = *(const float4*)&Xs[kk][64 + (cy << 2)];
      float4 b0 = *(const float4*)&Ws[kk][cx << 2];
      float4 b1 = *(const float4*)&Ws[kk][64 + (cx << 2)];
      float a8[8] = {a0.x, a0.y, a0.z, a0.w, a1.x, a1.y, a1.z, a1.w};
      float b8[8] = {b0.x, b0.y, b0.z, b0.w, b1.x, b1.y, b1.z, b1.w};
      #pragma unroll
      for (int i = 0; i < 8; i++)
        #pragma unroll
        for (int j = 0; j < 8; j++)
          acc[i][j] += a8[i] * b8[j];
    }
  }

  // per-thread argmax per token row (ascending vocab index: strict > keeps
  // the first maximum), then reduce across the 16 cx lanes, then atomic.
  #pragma unroll
  for (int i = 0; i < 8; i++) {
    int r = (i < 4) ? ((cy << 2) + i) : (64 + (cy << 2) + (i - 4));
    float s = -3.402823466e38f;
    int   bi = 0;
    #pragma unroll
    for (int j = 0; j < 8; j++) {
      int col = (j < 4) ? ((cx << 2) + j) : (64 + (cx << 2) + (j - 4));
      float v = acc[i][j];
      int idxv = vbase + col;
      if (v > s) { s = v; bi = idxv; }
    }
    #pragma unroll
    for (int off = 1; off < 16; off <<= 1) {
      float s2 = __shfl_xor(s, off, 64);
      int   b2 = __shfl_xor(bi, off, 64);
      if (s2 > s || (s2 == s && b2 < bi)) { s = s2; bi = b2; }
    }
    if (cx == 0) {
      unsigned int ub = __float_as_uint(s);
      ub = (ub & 0x80000000u) ? ~ub : (ub | 0x80000000u);  // monotone fp32->u32
      unsigned long long e =
          ((unsigned long long)ub << 32) | (unsigned long long)((unsigned int)~bi);
      atomicMax(&enc[(size_t)m * NBT + tbase + r], e);
    }
  }
}

// Per-(m,b): c(j) = longest common suffix of keys[0..j-1] with the full
// string (reversed Z-function, brute force with early exit; expected ~1
// compare per position for near-uniform codes).
// For each symbol x: L* = max c(j) over keys[j]==x ; rpos = min such j.
// Encodes ((2047-c)<<11)|j, atomicMin -> max c then min j.  Exactly
// equivalent to the reference SAM walk + e[state] (= min endpos).
__global__ __launch_bounds__(256) void table_kernel() {
  __shared__ int keys[NT];
  __shared__ unsigned int best[NKQK];
  const int mb = blockIdx.x;              // m*NB + b
  const int m = mb / NB, b = mb % NB;
  const int tid = threadIdx.x;
  const unsigned long long* ek = g_enc_k + (size_t)m * NBT + (size_t)b * NT;

  for (int j = tid; j < NT; j += 256)
    keys[j] = (int)~(unsigned int)(ek[j] & 0xFFFFFFFFull);
  for (int s = tid; s < NKQK; s += 256) best[s] = 0xFFFFFFFFu;
  __syncthreads();

  for (int j = tid; j < NT; j += 256) {
    int c = 0;
    while (c < j && keys[j - 1 - c] == keys[NT - 1 - c]) c++;
    unsigned int e2 = ((unsigned int)(2047 - c) << 11) | (unsigned int)j;
    atomicMin(&best[keys[j]], e2);
  }
  __syncthreads();

  for (int s = tid; s < NKQK; s += 256) {
    int ti[NTOPK], tv[NTOPK];
    #pragma unroll
    for (int k = 0; k < NTOPK; k++) { ti[k] = -1; tv[k] = 0; }
    unsigned int bv = best[s];
    if (bv != 0xFFFFFFFFu) {
      int rpos = (int)(bv & 2047u);
      int n = 0;
      for (int off = 1; off <= NTOPK; off++) {
        int idx = rpos + off;
        if (idx >= NT) break;
        int kc = keys[idx];
        if (kc != s) { ti[n] = idx; tv[n] = kc; n++; }
      }
    }
    int* pi = g_tab_idx + ((size_t)mb * NKQK + s) * NTOPK;
    int* pv = g_tab_val + ((size_t)mb * NKQK + s) * NTOPK;
    #pragma unroll
    for (int k = 0; k < NTOPK; k++) { pi[k] = ti[k]; pv[k] = tv[k]; }
  }
}

// out[b,t,:] = sum_m w[m] * sum_k Vemb[m][vcode(idx_k)] * Vemb[m][val_k]
// One block per token; thread owns 4 consecutive d (float4).
__global__ __launch_bounds__(256) void gather_kernel(
    const float* __restrict__ Vemb, const float* __restrict__ alpha,
    float* __restrict__ out)
{
  const int token = blockIdx.x;          // b*NT + t
  const int tid = threadIdx.x;
  const int b = token >> 11;             // NT = 2048
  const int d = tid * 4;

  float a0 = alpha[0], a1 = alpha[1];
  float mx = fmaxf(a0, a1);
  float e0 = __expf(a0 - mx), e1 = __expf(a1 - mx);
  float inv = 1.0f / (e0 + e1);
  float w[2] = {e0 * inv, e1 * inv};

  float4 acc = make_float4(0.f, 0.f, 0.f, 0.f);
  #pragma unroll
  for (int m = 0; m < NROUTE; m++) {
    int xq = (int)~(unsigned int)(g_enc_q[(size_t)m * NBT + token] & 0xFFFFFFFFull);
    const int mb = m * NB + b;
    const int* pi = g_tab_idx + ((size_t)mb * NKQK + xq) * NTOPK;
    const int* pv = g_tab_val + ((size_t)mb * NKQK + xq) * NTOPK;
    const float* Ve = Vemb + (size_t)m * (NVV + 1) * ND;
    float4 am = make_float4(0.f, 0.f, 0.f, 0.f);
    for (int k = 0; k < NTOPK; k++) {
      int idx = pi[k];
      if (idx < 0) break;
      int val = pv[k];
      int vcode = (int)~(unsigned int)(
          g_enc_v[(size_t)m * NBT + (size_t)b * NT + idx] & 0xFFFFFFFFull);
      float4 g = *(const float4*)(Ve + (size_t)vcode * ND + d);
      float4 l = *(const float4*)(Ve + (size_t)val * ND + d);
      am.x += g.x * l.x; am.y += g.y * l.y;
      am.z += g.z * l.z; am.w += g.w * l.w;
    }
    acc.x += w[m] * am.x; acc.y += w[m] * am.y;
    acc.z += w[m] * am.z; acc.w += w[m] * am.w;
  }
  *(float4*)(out + (size_t)token * ND + d) = acc;
}

extern "C" void kernel_launch(void* const* d_in, const int* in_sizes, int n_in,
                              void* d_out, int out_size, void* d_ws, size_t ws_size,
                              hipStream_t stream) {
  const float* x     = (const float*)d_in[0];
  const float* Wq    = (const float*)d_in[1];
  const float* Wk    = (const float*)d_in[2];
  const float* Wv    = (const float*)d_in[3];
  const float* Vemb  = (const float*)d_in[4];
  const float* alpha = (const float*)d_in[5];
  float* out = (float*)d_out;
  (void)in_sizes; (void)n_in; (void)out_size; (void)d_ws; (void)ws_size;

  zero_enc_kernel<<<(NROUTE*NBT + 255) / 256, 256, 0, stream>>>();

  dim3 gq(NBT / 128, NKQK / 128, NROUTE);   // 128x128 tiles
  dim3 gv(NBT / 128, NVV / 128, NROUTE);
  proj_argmax_kernel<<<gq, 256, 0, stream>>>(x, Wq, NKQK, 0);
  proj_argmax_kernel<<<gq, 256, 0, stream>>>(x, Wk, NKQK, 1);
  proj_argmax_kernel<<<gv, 256, 0, stream>>>(x, Wv, NVV, 2);

  table_kernel<<<NROUTE * NB, 256, 0, stream>>>();
  gather_kernel<<<NBT, 256, 0, stream>>>(Vemb, alpha, out);
}